// Round 6
// baseline (414.701 us; speedup 1.0000x reference)
//
#include <hip/hip_runtime.h>
#include <hip/hip_bf16.h>
#include <cstdint>

// Problem constants: B=2, H=16, L=2048, D=64
#define L_SEQ 2048
#define D_HEAD 64
#define N_HEADS 16
#define NBH 32   // B*H

typedef __attribute__((ext_vector_type(8))) __bf16 bf16x8;
typedef __attribute__((ext_vector_type(4))) __bf16 bf16x4;
typedef __attribute__((ext_vector_type(4))) float f32x4;

// ============================ prep kernels ============================

// Qb = bf16(Q * scale * log2e)  (so epilogue is exp2);  Kb = bf16(K)
__global__ __launch_bounds__(256) void prep_qk(const float* __restrict__ Q,
                                               const float* __restrict__ K,
                                               const float* __restrict__ scale_p,
                                               __bf16* __restrict__ Qb,
                                               __bf16* __restrict__ Kb) {
    const float c = scale_p[0] * 1.4426950408889634f;
    const size_t i = ((size_t)blockIdx.x * 256 + threadIdx.x) * 4;
    float4 q = *(const float4*)(Q + i);
    float4 k = *(const float4*)(K + i);
    __bf16 qo[4], ko[4];
    qo[0] = (__bf16)(q.x * c); qo[1] = (__bf16)(q.y * c);
    qo[2] = (__bf16)(q.z * c); qo[3] = (__bf16)(q.w * c);
    ko[0] = (__bf16)k.x; ko[1] = (__bf16)k.y; ko[2] = (__bf16)k.z; ko[3] = (__bf16)k.w;
    *(bf16x4*)(Qb + i) = *(bf16x4*)qo;
    *(bf16x4*)(Kb + i) = *(bf16x4*)ko;
}

// VbT[bh][d][k] = bf16(V[bh][k][d])  -- tiled transpose through LDS
__global__ __launch_bounds__(256) void prep_vt(const float* __restrict__ V,
                                               __bf16* __restrict__ VbT) {
    __shared__ __bf16 tile[64][72];
    const int bh = blockIdx.x >> 5;
    const int kt = blockIdx.x & 31;
    const int tid = threadIdx.x;
    const int r = tid >> 2;          // 0..63
    const int c = (tid & 3) * 16;    // 0,16,32,48
    const float* src = V + ((size_t)bh * L_SEQ + (size_t)kt * 64 + r) * D_HEAD + c;
    #pragma unroll
    for (int i = 0; i < 4; ++i) {
        float4 f = ((const float4*)src)[i];
        tile[r][c + i * 4 + 0] = (__bf16)f.x;
        tile[r][c + i * 4 + 1] = (__bf16)f.y;
        tile[r][c + i * 4 + 2] = (__bf16)f.z;
        tile[r][c + i * 4 + 3] = (__bf16)f.w;
    }
    __syncthreads();
    __bf16 out[16];
    #pragma unroll
    for (int j = 0; j < 16; ++j) out[j] = tile[c + j][r];   // [k][d] -> row d
    __bf16* dst = VbT + ((size_t)bh * D_HEAD + r) * L_SEQ + (size_t)kt * 64 + c;
    *(bf16x8*)dst       = *(bf16x8*)&out[0];
    *(bf16x8*)(dst + 8) = *(bf16x8*)&out[8];
}

// pack mask int32 -> bit per k: mp[row][kword], row in [B*L), 64 words/row
__global__ __launch_bounds__(256) void prep_mask(const int* __restrict__ mask,
                                                 unsigned int* __restrict__ mp) {
    const int wv   = blockIdx.x * 4 + (threadIdx.x >> 6);
    const int lane = threadIdx.x & 63;
    const int row  = wv >> 5;            // 0..4095
    const int k0   = (wv & 31) * 64;
    const int m = mask[(size_t)row * L_SEQ + k0 + lane];
    const unsigned long long b = __ballot(m != 0);
    if (lane < 2) mp[row * 64 + (k0 >> 5) + lane] = (unsigned int)(b >> (32 * lane));
}

// ============================ main kernel ============================
// Barrier-free (R3 dataflow) + full-line attn stores (R5 store path):
//  - K and V^T MFMA fragments loaded DIRECTLY from global (L2-resident bf16,
//    16B contiguous per lane) -> no __syncthreads anywhere, waves run free.
//  - wave-private P_lds bounce only (no block-level LDS dependencies).
//  - attn emitted from bf16 P via full-line NT stores: 4 rows x 256B per instr.
//  - XCD swizzle keeps each XCD's K/V^T slice hot in its private L2.
//  - s_setprio(1) around MFMA clusters: waves drift to independent phases,
//    so priority arbitration has something to do (guide: +4-7% on attn).
__global__ __launch_bounds__(256) void sdpa_main(
    const __bf16* __restrict__ Qb, const __bf16* __restrict__ Kb,
    const __bf16* __restrict__ VbT, const unsigned int* __restrict__ mp,
    float* __restrict__ ctx_out, float* __restrict__ attn_out)
{
    __shared__ __bf16 P_lds[4][16][72];

    const int tid = threadIdx.x;
    const int w   = tid >> 6;     // wave 0..3
    const int l   = tid & 63;     // lane
    const int r15 = l & 15;
    const int g   = l >> 4;

    // bijective XCD swizzle: 1024 blocks -> 128 consecutive per XCD
    const int bid = blockIdx.x;
    const int wg  = (bid & 7) * 128 + (bid >> 3);
    const int bh  = wg >> 5;
    const int qt  = wg & 31;
    const int b   = bh >> 4;
    const int q0  = qt * 64;

    // Q fragments (bf16, pre-scaled): lane holds A[row=r15][k=kk*32+8g+j]
    bf16x8 aq[2];
    {
        const __bf16* qrow = Qb + ((size_t)bh * L_SEQ + q0 + w * 16 + r15) * D_HEAD;
        aq[0] = *(const bf16x8*)(qrow + 8 * g);
        aq[1] = *(const bf16x8*)(qrow + 32 + 8 * g);
    }

    // fragment bases (direct-from-global)
    const __bf16* Kfrag = Kb  + (size_t)bh * L_SEQ * D_HEAD + (size_t)r15 * D_HEAD + 8 * g;
    const __bf16* Vfrag = VbT + (size_t)bh * D_HEAD * L_SEQ + (size_t)r15 * L_SEQ + 8 * g;

    const int qrow_base = q0 + w * 16 + g * 4;       // + r gives this lane's C rows
    const int mrow_base = b * L_SEQ + qrow_base;     // packed-mask rows

    float lsum[4] = {0.f, 0.f, 0.f, 0.f};

    // ================= Pass 1: row sums (no stores, no barriers) =================
    for (int ch = 0; ch < 32; ++ch) {
        const int k0 = ch * 64;
        uint2 mw[4];
        #pragma unroll
        for (int r = 0; r < 4; ++r)
            mw[r] = *(const uint2*)(mp + (size_t)(mrow_base + r) * 64 + 2 * ch);

        f32x4 acc[4] = {{0,0,0,0},{0,0,0,0},{0,0,0,0},{0,0,0,0}};
        __builtin_amdgcn_s_setprio(1);
        #pragma unroll
        for (int t = 0; t < 4; ++t) {
            const __bf16* kp = Kfrag + (size_t)(k0 + 16 * t) * D_HEAD;
            acc[t] = __builtin_amdgcn_mfma_f32_16x16x32_bf16(aq[0], *(const bf16x8*)kp,        acc[t], 0, 0, 0);
            acc[t] = __builtin_amdgcn_mfma_f32_16x16x32_bf16(aq[1], *(const bf16x8*)(kp + 32), acc[t], 0, 0, 0);
        }
        __builtin_amdgcn_s_setprio(0);
        #pragma unroll
        for (int t = 0; t < 4; ++t) {
            const int sh = (t & 1) * 16 + r15;
            #pragma unroll
            for (int r = 0; r < 4; ++r) {
                const unsigned int word = (t & 2) ? mw[r].y : mw[r].x;
                const float e = __builtin_exp2f(acc[t][r]);
                lsum[r] += ((word >> sh) & 1u) ? 0.f : e;
            }
        }
    }

    #pragma unroll
    for (int r = 0; r < 4; ++r) {
        float v = lsum[r];
        v += __shfl_xor(v, 1);
        v += __shfl_xor(v, 2);
        v += __shfl_xor(v, 4);
        v += __shfl_xor(v, 8);
        lsum[r] = 1.0f / v;
    }

    // ================= Pass 2: PV + full-line attn stores =================
    f32x4 ctx[4] = {{0,0,0,0},{0,0,0,0},{0,0,0,0},{0,0,0,0}};

    // attn store coords: lane stores cols sc..sc+3 of rows (4i + sr)
    const int sr = l >> 4;          // 0..3
    const int sc = (l & 15) * 4;    // 0..60
    float* abase = attn_out + ((size_t)bh * L_SEQ + q0 + w * 16) * L_SEQ;

    for (int ch = 0; ch < 32; ++ch) {
        const int k0 = ch * 64;
        uint2 mw[4];
        #pragma unroll
        for (int r = 0; r < 4; ++r)
            mw[r] = *(const uint2*)(mp + (size_t)(mrow_base + r) * 64 + 2 * ch);

        f32x4 acc[4] = {{0,0,0,0},{0,0,0,0},{0,0,0,0},{0,0,0,0}};
        __builtin_amdgcn_s_setprio(1);
        #pragma unroll
        for (int t = 0; t < 4; ++t) {
            const __bf16* kp = Kfrag + (size_t)(k0 + 16 * t) * D_HEAD;
            acc[t] = __builtin_amdgcn_mfma_f32_16x16x32_bf16(aq[0], *(const bf16x8*)kp,        acc[t], 0, 0, 0);
            acc[t] = __builtin_amdgcn_mfma_f32_16x16x32_bf16(aq[1], *(const bf16x8*)(kp + 32), acc[t], 0, 0, 0);
        }
        __builtin_amdgcn_s_setprio(0);

        // epilogue: p = exp2(s)*inv (masked), stash bf16 P (wave-private LDS)
        #pragma unroll
        for (int t = 0; t < 4; ++t) {
            const int sh = (t & 1) * 16 + r15;
            #pragma unroll
            for (int r = 0; r < 4; ++r) {
                const unsigned int word = (t & 2) ? mw[r].y : mw[r].x;
                float e = __builtin_exp2f(acc[t][r]) * lsum[r];
                e = ((word >> sh) & 1u) ? 0.f : e;
                P_lds[w][g * 4 + r][t * 16 + r15] = (__bf16)e;
            }
        }
        // PV: P_lds[w] wave-private; compiler inserts the lgkm wait.
        const bf16x8 pa0 = *(const bf16x8*)&P_lds[w][r15][8 * g];
        const bf16x8 pa1 = *(const bf16x8*)&P_lds[w][r15][32 + 8 * g];
        __builtin_amdgcn_s_setprio(1);
        #pragma unroll
        for (int t2 = 0; t2 < 4; ++t2) {
            const __bf16* vp = Vfrag + (size_t)(16 * t2) * L_SEQ + k0;
            ctx[t2] = __builtin_amdgcn_mfma_f32_16x16x32_bf16(pa0, *(const bf16x8*)vp,        ctx[t2], 0, 0, 0);
            ctx[t2] = __builtin_amdgcn_mfma_f32_16x16x32_bf16(pa1, *(const bf16x8*)(vp + 32), ctx[t2], 0, 0, 0);
        }
        __builtin_amdgcn_s_setprio(0);

        // attn store from P_lds: per instr 4 rows x 256B contiguous (full lines)
        #pragma unroll
        for (int i = 0; i < 4; ++i) {
            const int row = 4 * i + sr;
            const uint2 raw = *(const uint2*)&P_lds[w][row][sc];
            f32x4 o;
            o[0] = __uint_as_float(raw.x << 16);
            o[1] = __uint_as_float(raw.x & 0xFFFF0000u);
            o[2] = __uint_as_float(raw.y << 16);
            o[3] = __uint_as_float(raw.y & 0xFFFF0000u);
            __builtin_nontemporal_store(o, (f32x4*)(abase + (size_t)row * L_SEQ + k0 + sc));
        }
    }

    // ctx store (16 MB total -- minor)
    #pragma unroll
    for (int t2 = 0; t2 < 4; ++t2) {
        #pragma unroll
        for (int r = 0; r < 4; ++r) {
            __builtin_nontemporal_store(
                ctx[t2][r],
                &ctx_out[((size_t)bh * L_SEQ + qrow_base + r) * D_HEAD + t2 * 16 + r15]);
        }
    }
}

// ===================== fallback (round-1 verified kernel) =====================
__global__ __launch_bounds__(256) void sdpa_fallback(
    const float* __restrict__ Q, const float* __restrict__ K,
    const float* __restrict__ V, const float* __restrict__ scale_p,
    const int* __restrict__ mask, float* __restrict__ ctx_out,
    float* __restrict__ attn_out)
{
    __shared__ __bf16 K_lds[64][72];
    __shared__ __bf16 V_lds[64][72];
    __shared__ __bf16 P_lds[4][16][72];

    const int tid = threadIdx.x;
    const int w   = tid >> 6;
    const int l   = tid & 63;
    const int r15 = l & 15;
    const int g   = l >> 4;

    const int qt = blockIdx.x & 31;
    const int bh = blockIdx.x >> 5;
    const int b  = bh >> 4;
    const int q0 = qt * 64;

    const float scale = *scale_p;
    const float* Qp = Q + (size_t)bh * L_SEQ * D_HEAD;
    const float* Kp = K + (size_t)bh * L_SEQ * D_HEAD;
    const float* Vp = V + (size_t)bh * L_SEQ * D_HEAD;
    const int*   Mp = mask + (size_t)b * L_SEQ * L_SEQ;

    bf16x8 aq[2];
    {
        const float* qrow = Qp + (size_t)(q0 + w * 16 + r15) * D_HEAD;
        #pragma unroll
        for (int kk = 0; kk < 2; ++kk) {
            const float* s = qrow + kk * 32 + g * 8;
            bf16x8 v;
            #pragma unroll
            for (int j = 0; j < 8; ++j) v[j] = (__bf16)s[j];
            aq[kk] = v;
        }
    }

    const int srow = tid >> 2;
    const int scol = (tid & 3) * 16;
    const int qrow_base = q0 + w * 16 + g * 4;

    float lsum[4] = {0.f, 0.f, 0.f, 0.f};

    for (int ch = 0; ch < 32; ++ch) {
        const int k0 = ch * 64;
        __syncthreads();
        {
            const float4* s4 = (const float4*)(Kp + (size_t)(k0 + srow) * D_HEAD + scol);
            __bf16 tmp[16];
            #pragma unroll
            for (int i = 0; i < 4; ++i) {
                float4 f = s4[i];
                tmp[i*4+0] = (__bf16)f.x; tmp[i*4+1] = (__bf16)f.y;
                tmp[i*4+2] = (__bf16)f.z; tmp[i*4+3] = (__bf16)f.w;
            }
            *(bf16x8*)&K_lds[srow][scol]     = *(bf16x8*)&tmp[0];
            *(bf16x8*)&K_lds[srow][scol + 8] = *(bf16x8*)&tmp[8];
        }
        __syncthreads();

        f32x4 acc[4] = {{0,0,0,0},{0,0,0,0},{0,0,0,0},{0,0,0,0}};
        #pragma unroll
        for (int t = 0; t < 4; ++t) {
            #pragma unroll
            for (int kk = 0; kk < 2; ++kk) {
                bf16x8 bk = *(const bf16x8*)&K_lds[t * 16 + r15][kk * 32 + g * 8];
                acc[t] = __builtin_amdgcn_mfma_f32_16x16x32_bf16(aq[kk], bk, acc[t], 0, 0, 0);
            }
        }
        #pragma unroll
        for (int t = 0; t < 4; ++t) {
            const int kcol = k0 + t * 16 + r15;
            #pragma unroll
            for (int r = 0; r < 4; ++r) {
                const int mk = Mp[(size_t)(qrow_base + r) * L_SEQ + kcol];
                const float s = acc[t][r] * scale;
                const float e = mk ? 0.0f : __expf(s);
                lsum[r] += e;
            }
        }
    }

    #pragma unroll
    for (int r = 0; r < 4; ++r) {
        float v = lsum[r];
        v += __shfl_xor(v, 1);
        v += __shfl_xor(v, 2);
        v += __shfl_xor(v, 4);
        v += __shfl_xor(v, 8);
        lsum[r] = 1.0f / v;
    }

    f32x4 ctx[4] = {{0,0,0,0},{0,0,0,0},{0,0,0,0},{0,0,0,0}};
    for (int ch = 0; ch < 32; ++ch) {
        const int k0 = ch * 64;
        __syncthreads();
        {
            const float4* s4 = (const float4*)(Kp + (size_t)(k0 + srow) * D_HEAD + scol);
            __bf16 tmp[16];
            #pragma unroll
            for (int i = 0; i < 4; ++i) {
                float4 f = s4[i];
                tmp[i*4+0] = (__bf16)f.x; tmp[i*4+1] = (__bf16)f.y;
                tmp[i*4+2] = (__bf16)f.z; tmp[i*4+3] = (__bf16)f.w;
            }
            *(bf16x8*)&K_lds[srow][scol]     = *(bf16x8*)&tmp[0];
            *(bf16x8*)&K_lds[srow][scol + 8] = *(bf16x8*)&tmp[8];
        }
        {
            const float4* s4 = (const float4*)(Vp + (size_t)(k0 + srow) * D_HEAD + scol);
            #pragma unroll
            for (int i = 0; i < 4; ++i) {
                float4 f = s4[i];
                V_lds[scol + i*4 + 0][srow] = (__bf16)f.x;
                V_lds[scol + i*4 + 1][srow] = (__bf16)f.y;
                V_lds[scol + i*4 + 2][srow] = (__bf16)f.z;
                V_lds[scol + i*4 + 3][srow] = (__bf16)f.w;
            }
        }
        __syncthreads();

        f32x4 acc[4] = {{0,0,0,0},{0,0,0,0},{0,0,0,0},{0,0,0,0}};
        #pragma unroll
        for (int t = 0; t < 4; ++t) {
            #pragma unroll
            for (int kk = 0; kk < 2; ++kk) {
                bf16x8 bk = *(const bf16x8*)&K_lds[t * 16 + r15][kk * 32 + g * 8];
                acc[t] = __builtin_amdgcn_mfma_f32_16x16x32_bf16(aq[kk], bk, acc[t], 0, 0, 0);
            }
        }
        #pragma unroll
        for (int t = 0; t < 4; ++t) {
            const int kcol = k0 + t * 16 + r15;
            #pragma unroll
            for (int r = 0; r < 4; ++r) {
                const int mk = Mp[(size_t)(qrow_base + r) * L_SEQ + kcol];
                const float s = acc[t][r] * scale;
                const float p = mk ? 0.0f : __expf(s) * lsum[r];
                __builtin_nontemporal_store(
                    p, &attn_out[((size_t)bh * L_SEQ + qrow_base + r) * L_SEQ + kcol]);
                P_lds[w][g * 4 + r][t * 16 + r15] = (__bf16)p;
            }
        }
        #pragma unroll
        for (int t2 = 0; t2 < 4; ++t2) {
            #pragma unroll
            for (int kk = 0; kk < 2; ++kk) {
                bf16x8 pa = *(const bf16x8*)&P_lds[w][r15][kk * 32 + g * 8];
                bf16x8 pv = *(const bf16x8*)&V_lds[t2 * 16 + r15][kk * 32 + g * 8];
                ctx[t2] = __builtin_amdgcn_mfma_f32_16x16x32_bf16(pa, pv, ctx[t2], 0, 0, 0);
            }
        }
    }

    #pragma unroll
    for (int t2 = 0; t2 < 4; ++t2) {
        #pragma unroll
        for (int r = 0; r < 4; ++r) {
            __builtin_nontemporal_store(
                ctx[t2][r],
                &ctx_out[((size_t)bh * L_SEQ + qrow_base + r) * D_HEAD + t2 * 16 + r15]);
        }
    }
}

// ============================ launcher ============================
extern "C" void kernel_launch(void* const* d_in, const int* in_sizes, int n_in,
                              void* d_out, int out_size, void* d_ws, size_t ws_size,
                              hipStream_t stream) {
    const float* Q     = (const float*)d_in[0];
    const float* K     = (const float*)d_in[1];
    const float* V     = (const float*)d_in[2];
    const float* scale = (const float*)d_in[3];
    const int*   mask  = (const int*)d_in[4];

    float* ctx_out  = (float*)d_out;
    float* attn_out = (float*)d_out + (size_t)NBH * L_SEQ * D_HEAD;

    const size_t bfbytes = (size_t)NBH * L_SEQ * D_HEAD * 2;  // 8,388,608
    const size_t need = 3 * bfbytes + (size_t)2 * L_SEQ * (L_SEQ / 32) * 4; // +1MB mask bits

    if (ws_size >= need) {
        __bf16* Qb  = (__bf16*)d_ws;
        __bf16* Kb  = Qb + (size_t)NBH * L_SEQ * D_HEAD;
        __bf16* VbT = Kb + (size_t)NBH * L_SEQ * D_HEAD;
        unsigned int* mp = (unsigned int*)((char*)d_ws + 3 * bfbytes);

        hipLaunchKernelGGL(prep_qk,   dim3(4096),  dim3(256), 0, stream, Q, K, scale, Qb, Kb);
        hipLaunchKernelGGL(prep_vt,   dim3(1024),  dim3(256), 0, stream, V, VbT);
        hipLaunchKernelGGL(prep_mask, dim3(32768), dim3(256), 0, stream, mask, mp);
        hipLaunchKernelGGL(sdpa_main, dim3(1024),  dim3(256), 0, stream,
                           Qb, Kb, VbT, mp, ctx_out, attn_out);
    } else {
        hipLaunchKernelGGL(sdpa_fallback, dim3(1024), dim3(256), 0, stream,
                           Q, K, V, scale, mask, ctx_out, attn_out);
    }
}

// Round 7
// 205.231 us; speedup vs baseline: 2.0207x; 2.0207x over previous
//
#include <hip/hip_runtime.h>
#include <hip/hip_bf16.h>
#include <cstdint>

// Problem constants: B=2, H=16, L=2048, D=64
#define L_SEQ 2048
#define D_HEAD 64
#define N_HEADS 16
#define NBH 32   // B*H

typedef __attribute__((ext_vector_type(8))) __bf16 bf16x8;
typedef __attribute__((ext_vector_type(4))) __bf16 bf16x4;
typedef __attribute__((ext_vector_type(4))) float f32x4;

// ============================ prep kernels ============================

// Qb = bf16(Q * scale * log2e)  (so epilogue is exp2);  Kb = bf16(K)
__global__ __launch_bounds__(256) void prep_qk(const float* __restrict__ Q,
                                               const float* __restrict__ K,
                                               const float* __restrict__ scale_p,
                                               __bf16* __restrict__ Qb,
                                               __bf16* __restrict__ Kb) {
    const float c = scale_p[0] * 1.4426950408889634f;
    const size_t i = ((size_t)blockIdx.x * 256 + threadIdx.x) * 4;
    float4 q = *(const float4*)(Q + i);
    float4 k = *(const float4*)(K + i);
    __bf16 qo[4], ko[4];
    qo[0] = (__bf16)(q.x * c); qo[1] = (__bf16)(q.y * c);
    qo[2] = (__bf16)(q.z * c); qo[3] = (__bf16)(q.w * c);
    ko[0] = (__bf16)k.x; ko[1] = (__bf16)k.y; ko[2] = (__bf16)k.z; ko[3] = (__bf16)k.w;
    *(bf16x4*)(Qb + i) = *(bf16x4*)qo;
    *(bf16x4*)(Kb + i) = *(bf16x4*)ko;
}

// VbT[bh][d][k] = bf16(V[bh][k][d])  -- tiled transpose through LDS
__global__ __launch_bounds__(256) void prep_vt(const float* __restrict__ V,
                                               __bf16* __restrict__ VbT) {
    __shared__ __bf16 tile[64][72];
    const int bh = blockIdx.x >> 5;
    const int kt = blockIdx.x & 31;
    const int tid = threadIdx.x;
    const int r = tid >> 2;          // 0..63
    const int c = (tid & 3) * 16;    // 0,16,32,48
    const float* src = V + ((size_t)bh * L_SEQ + (size_t)kt * 64 + r) * D_HEAD + c;
    #pragma unroll
    for (int i = 0; i < 4; ++i) {
        float4 f = ((const float4*)src)[i];
        tile[r][c + i * 4 + 0] = (__bf16)f.x;
        tile[r][c + i * 4 + 1] = (__bf16)f.y;
        tile[r][c + i * 4 + 2] = (__bf16)f.z;
        tile[r][c + i * 4 + 3] = (__bf16)f.w;
    }
    __syncthreads();
    __bf16 out[16];
    #pragma unroll
    for (int j = 0; j < 16; ++j) out[j] = tile[c + j][r];   // [k][d] -> row d
    __bf16* dst = VbT + ((size_t)bh * D_HEAD + r) * L_SEQ + (size_t)kt * 64 + c;
    *(bf16x8*)dst       = *(bf16x8*)&out[0];
    *(bf16x8*)(dst + 8) = *(bf16x8*)&out[8];
}

// pack mask int32 -> bit per k: mp[row][kword], row in [B*L), 64 words/row
__global__ __launch_bounds__(256) void prep_mask(const int* __restrict__ mask,
                                                 unsigned int* __restrict__ mp) {
    const int wv   = blockIdx.x * 4 + (threadIdx.x >> 6);
    const int lane = threadIdx.x & 63;
    const int row  = wv >> 5;            // 0..4095
    const int k0   = (wv & 31) * 64;
    const int m = mask[(size_t)row * L_SEQ + k0 + lane];
    const unsigned long long b = __ballot(m != 0);
    if (lane < 2) mp[row * 64 + (k0 >> 5) + lane] = (unsigned int)(b >> (32 * lane));
}

// ============================ main kernel ============================
// R5 structure (LDS-staged K/V — direct-from-global operands proven 2x slower
// in R3/R4/R6) + T14 async-STAGE split: issue tile t+1's global loads into
// registers BEFORE computing tile t; ds_write them after the post-compute
// barrier. HBM/L2 latency hides under MFMA+exp+stores instead of sitting on
// the critical path between two barriers.
//  - full-line NT attn stores from bf16 P_lds (R5's +50% win, kept)
//  - packed bitmask, bf16 pre-scaled Q (exp2 epilogue), pre-transposed V
//  - bijective XCD swizzle: 4 consecutive heads per XCD -> K/V slice fits L2
__global__ __launch_bounds__(256) void sdpa_main(
    const __bf16* __restrict__ Qb, const __bf16* __restrict__ Kb,
    const __bf16* __restrict__ VbT, const unsigned int* __restrict__ mp,
    float* __restrict__ ctx_out, float* __restrict__ attn_out)
{
    __shared__ __bf16 K_lds[64][72];
    __shared__ __bf16 V_lds[64][72];   // [d][k_local]
    __shared__ __bf16 P_lds[4][16][72];

    const int tid = threadIdx.x;
    const int w   = tid >> 6;     // wave 0..3
    const int l   = tid & 63;     // lane
    const int r15 = l & 15;
    const int g   = l >> 4;

    // bijective XCD swizzle: 1024 blocks -> 128 consecutive work-ids per XCD
    const int bid = blockIdx.x;
    const int wg  = (bid & 7) * 128 + (bid >> 3);
    const int bh  = wg >> 5;
    const int qt  = wg & 31;
    const int b   = bh >> 4;
    const int q0  = qt * 64;

    const __bf16* Kp = Kb  + (size_t)bh * L_SEQ * D_HEAD;
    const __bf16* Vp = VbT + (size_t)bh * D_HEAD * L_SEQ;

    // Q fragments (bf16, pre-scaled): lane holds A[row=r15][k=kk*32+8g+j]
    bf16x8 aq[2];
    {
        const __bf16* qrow = Qb + ((size_t)bh * L_SEQ + q0 + w * 16 + r15) * D_HEAD;
        aq[0] = *(const bf16x8*)(qrow + 8 * g);
        aq[1] = *(const bf16x8*)(qrow + 32 + 8 * g);
    }

    // staging decomposition: 64x64 bf16 tile, thread -> 16 consecutive bf16
    const int srow = tid >> 2;         // 0..63
    const int scol = (tid & 3) * 16;   // 0,16,32,48

    const int qrow_base = q0 + w * 16 + g * 4;           // + r gives C rows
    const int mrow_base = b * L_SEQ + qrow_base;         // packed mask rows

    float lsum[4] = {0.f, 0.f, 0.f, 0.f};

    // ================= Pass 1: row sums (K staging pipelined) =================
    {
        // prologue: stage tile 0
        bf16x8 ka = *(const bf16x8*)(Kp + (size_t)srow * D_HEAD + scol);
        bf16x8 kb = *(const bf16x8*)(Kp + (size_t)srow * D_HEAD + scol + 8);
        *(bf16x8*)&K_lds[srow][scol]     = ka;
        *(bf16x8*)&K_lds[srow][scol + 8] = kb;
        __syncthreads();

        for (int ch = 0; ch < 32; ++ch) {
            // issue next tile's loads NOW (latency hides under compute)
            const int chn = (ch < 31) ? ch + 1 : ch;
            const __bf16* knp = Kp + (size_t)(chn * 64 + srow) * D_HEAD + scol;
            ka = *(const bf16x8*)knp;
            kb = *(const bf16x8*)(knp + 8);

            uint2 mw[4];
            #pragma unroll
            for (int r = 0; r < 4; ++r)
                mw[r] = *(const uint2*)(mp + (size_t)(mrow_base + r) * 64 + 2 * ch);

            f32x4 acc[4] = {{0,0,0,0},{0,0,0,0},{0,0,0,0},{0,0,0,0}};
            #pragma unroll
            for (int t = 0; t < 4; ++t) {
                #pragma unroll
                for (int kk = 0; kk < 2; ++kk) {
                    bf16x8 bk = *(const bf16x8*)&K_lds[t * 16 + r15][kk * 32 + g * 8];
                    acc[t] = __builtin_amdgcn_mfma_f32_16x16x32_bf16(aq[kk], bk, acc[t], 0, 0, 0);
                }
            }
            #pragma unroll
            for (int t = 0; t < 4; ++t) {
                const int sh = (t & 1) * 16 + r15;
                #pragma unroll
                for (int r = 0; r < 4; ++r) {
                    const unsigned int word = (t & 2) ? mw[r].y : mw[r].x;
                    const float e = __builtin_exp2f(acc[t][r]);
                    lsum[r] += ((word >> sh) & 1u) ? 0.f : e;
                }
            }

            __syncthreads();                    // all reads of tile ch done
            *(bf16x8*)&K_lds[srow][scol]     = ka;   // write tile ch+1
            *(bf16x8*)&K_lds[srow][scol + 8] = kb;
            __syncthreads();                    // tile ch+1 visible
        }
    }

    #pragma unroll
    for (int r = 0; r < 4; ++r) {
        float v = lsum[r];
        v += __shfl_xor(v, 1);
        v += __shfl_xor(v, 2);
        v += __shfl_xor(v, 4);
        v += __shfl_xor(v, 8);
        lsum[r] = 1.0f / v;
    }

    // ================= Pass 2: PV + full-line attn stores (pipelined) =========
    f32x4 ctx[4] = {{0,0,0,0},{0,0,0,0},{0,0,0,0},{0,0,0,0}};

    // attn store coords: lane stores cols sc..sc+3 of rows (4i + sr)
    const int sr = l >> 4;          // 0..3
    const int sc = (l & 15) * 4;    // 0..60
    float* abase = attn_out + ((size_t)bh * L_SEQ + q0 + w * 16) * L_SEQ;

    {
        // prologue: stage tile 0 (K and V)
        bf16x8 ka = *(const bf16x8*)(Kp + (size_t)srow * D_HEAD + scol);
        bf16x8 kb = *(const bf16x8*)(Kp + (size_t)srow * D_HEAD + scol + 8);
        bf16x8 va = *(const bf16x8*)(Vp + (size_t)srow * L_SEQ + scol);
        bf16x8 vb = *(const bf16x8*)(Vp + (size_t)srow * L_SEQ + scol + 8);
        __syncthreads();   // pass-1's last LDS reads are long done, but be safe
        *(bf16x8*)&K_lds[srow][scol]     = ka;
        *(bf16x8*)&K_lds[srow][scol + 8] = kb;
        *(bf16x8*)&V_lds[srow][scol]     = va;
        *(bf16x8*)&V_lds[srow][scol + 8] = vb;
        __syncthreads();

        for (int ch = 0; ch < 32; ++ch) {
            const int k0 = ch * 64;
            // issue next tile's loads NOW
            const int chn = (ch < 31) ? ch + 1 : ch;
            const __bf16* knp = Kp + (size_t)(chn * 64 + srow) * D_HEAD + scol;
            const __bf16* vnp = Vp + (size_t)srow * L_SEQ + chn * 64 + scol;
            ka = *(const bf16x8*)knp;
            kb = *(const bf16x8*)(knp + 8);
            va = *(const bf16x8*)vnp;
            vb = *(const bf16x8*)(vnp + 8);

            uint2 mw[4];
            #pragma unroll
            for (int r = 0; r < 4; ++r)
                mw[r] = *(const uint2*)(mp + (size_t)(mrow_base + r) * 64 + 2 * ch);

            f32x4 acc[4] = {{0,0,0,0},{0,0,0,0},{0,0,0,0},{0,0,0,0}};
            #pragma unroll
            for (int t = 0; t < 4; ++t) {
                #pragma unroll
                for (int kk = 0; kk < 2; ++kk) {
                    bf16x8 bk = *(const bf16x8*)&K_lds[t * 16 + r15][kk * 32 + g * 8];
                    acc[t] = __builtin_amdgcn_mfma_f32_16x16x32_bf16(aq[kk], bk, acc[t], 0, 0, 0);
                }
            }
            // epilogue: p = exp2(s)*inv (masked) -> bf16 P (wave-private LDS)
            #pragma unroll
            for (int t = 0; t < 4; ++t) {
                const int sh = (t & 1) * 16 + r15;
                #pragma unroll
                for (int r = 0; r < 4; ++r) {
                    const unsigned int word = (t & 2) ? mw[r].y : mw[r].x;
                    float e = __builtin_exp2f(acc[t][r]) * lsum[r];
                    e = ((word >> sh) & 1u) ? 0.f : e;
                    P_lds[w][g * 4 + r][t * 16 + r15] = (__bf16)e;
                }
            }
            // PV: P_lds[w] wave-private; compiler inserts the lgkm wait.
            const bf16x8 pa0 = *(const bf16x8*)&P_lds[w][r15][8 * g];
            const bf16x8 pa1 = *(const bf16x8*)&P_lds[w][r15][32 + 8 * g];
            #pragma unroll
            for (int t2 = 0; t2 < 4; ++t2) {
                bf16x8 pv0 = *(const bf16x8*)&V_lds[t2 * 16 + r15][8 * g];
                bf16x8 pv1 = *(const bf16x8*)&V_lds[t2 * 16 + r15][32 + 8 * g];
                ctx[t2] = __builtin_amdgcn_mfma_f32_16x16x32_bf16(pa0, pv0, ctx[t2], 0, 0, 0);
                ctx[t2] = __builtin_amdgcn_mfma_f32_16x16x32_bf16(pa1, pv1, ctx[t2], 0, 0, 0);
            }
            // attn store from P_lds: 4 rows x 256B contiguous per instr (full lines)
            #pragma unroll
            for (int i = 0; i < 4; ++i) {
                const int row = 4 * i + sr;
                const uint2 raw = *(const uint2*)&P_lds[w][row][sc];
                f32x4 o;
                o[0] = __uint_as_float(raw.x << 16);
                o[1] = __uint_as_float(raw.x & 0xFFFF0000u);
                o[2] = __uint_as_float(raw.y << 16);
                o[3] = __uint_as_float(raw.y & 0xFFFF0000u);
                __builtin_nontemporal_store(o, (f32x4*)(abase + (size_t)row * L_SEQ + k0 + sc));
            }

            __syncthreads();                    // all reads of tile ch done
            *(bf16x8*)&K_lds[srow][scol]     = ka;   // write tile ch+1
            *(bf16x8*)&K_lds[srow][scol + 8] = kb;
            *(bf16x8*)&V_lds[srow][scol]     = va;
            *(bf16x8*)&V_lds[srow][scol + 8] = vb;
            __syncthreads();                    // tile ch+1 visible
        }
    }

    // ctx store (16 MB total -- minor)
    #pragma unroll
    for (int t2 = 0; t2 < 4; ++t2) {
        #pragma unroll
        for (int r = 0; r < 4; ++r) {
            __builtin_nontemporal_store(
                ctx[t2][r],
                &ctx_out[((size_t)bh * L_SEQ + qrow_base + r) * D_HEAD + t2 * 16 + r15]);
        }
    }
}

// ===================== fallback (round-1 verified kernel) =====================
__global__ __launch_bounds__(256) void sdpa_fallback(
    const float* __restrict__ Q, const float* __restrict__ K,
    const float* __restrict__ V, const float* __restrict__ scale_p,
    const int* __restrict__ mask, float* __restrict__ ctx_out,
    float* __restrict__ attn_out)
{
    __shared__ __bf16 K_lds[64][72];
    __shared__ __bf16 V_lds[64][72];
    __shared__ __bf16 P_lds[4][16][72];

    const int tid = threadIdx.x;
    const int w   = tid >> 6;
    const int l   = tid & 63;
    const int r15 = l & 15;
    const int g   = l >> 4;

    const int qt = blockIdx.x & 31;
    const int bh = blockIdx.x >> 5;
    const int b  = bh >> 4;
    const int q0 = qt * 64;

    const float scale = *scale_p;
    const float* Qp = Q + (size_t)bh * L_SEQ * D_HEAD;
    const float* Kp = K + (size_t)bh * L_SEQ * D_HEAD;
    const float* Vp = V + (size_t)bh * L_SEQ * D_HEAD;
    const int*   Mp = mask + (size_t)b * L_SEQ * L_SEQ;

    bf16x8 aq[2];
    {
        const float* qrow = Qp + (size_t)(q0 + w * 16 + r15) * D_HEAD;
        #pragma unroll
        for (int kk = 0; kk < 2; ++kk) {
            const float* s = qrow + kk * 32 + g * 8;
            bf16x8 v;
            #pragma unroll
            for (int j = 0; j < 8; ++j) v[j] = (__bf16)s[j];
            aq[kk] = v;
        }
    }

    const int srow = tid >> 2;
    const int scol = (tid & 3) * 16;
    const int qrow_base = q0 + w * 16 + g * 4;

    float lsum[4] = {0.f, 0.f, 0.f, 0.f};

    for (int ch = 0; ch < 32; ++ch) {
        const int k0 = ch * 64;
        __syncthreads();
        {
            const float4* s4 = (const float4*)(Kp + (size_t)(k0 + srow) * D_HEAD + scol);
            __bf16 tmp[16];
            #pragma unroll
            for (int i = 0; i < 4; ++i) {
                float4 f = s4[i];
                tmp[i*4+0] = (__bf16)f.x; tmp[i*4+1] = (__bf16)f.y;
                tmp[i*4+2] = (__bf16)f.z; tmp[i*4+3] = (__bf16)f.w;
            }
            *(bf16x8*)&K_lds[srow][scol]     = *(bf16x8*)&tmp[0];
            *(bf16x8*)&K_lds[srow][scol + 8] = *(bf16x8*)&tmp[8];
        }
        __syncthreads();

        f32x4 acc[4] = {{0,0,0,0},{0,0,0,0},{0,0,0,0},{0,0,0,0}};
        #pragma unroll
        for (int t = 0; t < 4; ++t) {
            #pragma unroll
            for (int kk = 0; kk < 2; ++kk) {
                bf16x8 bk = *(const bf16x8*)&K_lds[t * 16 + r15][kk * 32 + g * 8];
                acc[t] = __builtin_amdgcn_mfma_f32_16x16x32_bf16(aq[kk], bk, acc[t], 0, 0, 0);
            }
        }
        #pragma unroll
        for (int t = 0; t < 4; ++t) {
            const int kcol = k0 + t * 16 + r15;
            #pragma unroll
            for (int r = 0; r < 4; ++r) {
                const int mk = Mp[(size_t)(qrow_base + r) * L_SEQ + kcol];
                const float s = acc[t][r] * scale;
                const float e = mk ? 0.0f : __expf(s);
                lsum[r] += e;
            }
        }
    }

    #pragma unroll
    for (int r = 0; r < 4; ++r) {
        float v = lsum[r];
        v += __shfl_xor(v, 1);
        v += __shfl_xor(v, 2);
        v += __shfl_xor(v, 4);
        v += __shfl_xor(v, 8);
        lsum[r] = 1.0f / v;
    }

    f32x4 ctx[4] = {{0,0,0,0},{0,0,0,0},{0,0,0,0},{0,0,0,0}};
    for (int ch = 0; ch < 32; ++ch) {
        const int k0 = ch * 64;
        __syncthreads();
        {
            const float4* s4 = (const float4*)(Kp + (size_t)(k0 + srow) * D_HEAD + scol);
            __bf16 tmp[16];
            #pragma unroll
            for (int i = 0; i < 4; ++i) {
                float4 f = s4[i];
                tmp[i*4+0] = (__bf16)f.x; tmp[i*4+1] = (__bf16)f.y;
                tmp[i*4+2] = (__bf16)f.z; tmp[i*4+3] = (__bf16)f.w;
            }
            *(bf16x8*)&K_lds[srow][scol]     = *(bf16x8*)&tmp[0];
            *(bf16x8*)&K_lds[srow][scol + 8] = *(bf16x8*)&tmp[8];
        }
        {
            const float4* s4 = (const float4*)(Vp + (size_t)(k0 + srow) * D_HEAD + scol);
            #pragma unroll
            for (int i = 0; i < 4; ++i) {
                float4 f = s4[i];
                V_lds[scol + i*4 + 0][srow] = (__bf16)f.x;
                V_lds[scol + i*4 + 1][srow] = (__bf16)f.y;
                V_lds[scol + i*4 + 2][srow] = (__bf16)f.z;
                V_lds[scol + i*4 + 3][srow] = (__bf16)f.w;
            }
        }
        __syncthreads();

        f32x4 acc[4] = {{0,0,0,0},{0,0,0,0},{0,0,0,0},{0,0,0,0}};
        #pragma unroll
        for (int t = 0; t < 4; ++t) {
            #pragma unroll
            for (int kk = 0; kk < 2; ++kk) {
                bf16x8 bk = *(const bf16x8*)&K_lds[t * 16 + r15][kk * 32 + g * 8];
                acc[t] = __builtin_amdgcn_mfma_f32_16x16x32_bf16(aq[kk], bk, acc[t], 0, 0, 0);
            }
        }
        #pragma unroll
        for (int t = 0; t < 4; ++t) {
            const int kcol = k0 + t * 16 + r15;
            #pragma unroll
            for (int r = 0; r < 4; ++r) {
                const int mk = Mp[(size_t)(qrow_base + r) * L_SEQ + kcol];
                const float s = acc[t][r] * scale;
                const float p = mk ? 0.0f : __expf(s) * lsum[r];
                __builtin_nontemporal_store(
                    p, &attn_out[((size_t)bh * L_SEQ + qrow_base + r) * L_SEQ + kcol]);
                P_lds[w][g * 4 + r][t * 16 + r15] = (__bf16)p;
            }
        }
        #pragma unroll
        for (int t2 = 0; t2 < 4; ++t2) {
            #pragma unroll
            for (int kk = 0; kk < 2; ++kk) {
                bf16x8 pa = *(const bf16x8*)&P_lds[w][r15][kk * 32 + g * 8];
                bf16x8 pv = *(const bf16x8*)&V_lds[t2 * 16 + r15][kk * 32 + g * 8];
                ctx[t2] = __builtin_amdgcn_mfma_f32_16x16x32_bf16(pa, pv, ctx[t2], 0, 0, 0);
            }
        }
    }

    #pragma unroll
    for (int t2 = 0; t2 < 4; ++t2) {
        #pragma unroll
        for (int r = 0; r < 4; ++r) {
            __builtin_nontemporal_store(
                ctx[t2][r],
                &ctx_out[((size_t)bh * L_SEQ + qrow_base + r) * D_HEAD + t2 * 16 + r15]);
        }
    }
}

// ============================ launcher ============================
extern "C" void kernel_launch(void* const* d_in, const int* in_sizes, int n_in,
                              void* d_out, int out_size, void* d_ws, size_t ws_size,
                              hipStream_t stream) {
    const float* Q     = (const float*)d_in[0];
    const float* K     = (const float*)d_in[1];
    const float* V     = (const float*)d_in[2];
    const float* scale = (const float*)d_in[3];
    const int*   mask  = (const int*)d_in[4];

    float* ctx_out  = (float*)d_out;
    float* attn_out = (float*)d_out + (size_t)NBH * L_SEQ * D_HEAD;

    const size_t bfbytes = (size_t)NBH * L_SEQ * D_HEAD * 2;  // 8,388,608
    const size_t need = 3 * bfbytes + (size_t)2 * L_SEQ * (L_SEQ / 32) * 4; // +1MB mask bits

    if (ws_size >= need) {
        __bf16* Qb  = (__bf16*)d_ws;
        __bf16* Kb  = Qb + (size_t)NBH * L_SEQ * D_HEAD;
        __bf16* VbT = Kb + (size_t)NBH * L_SEQ * D_HEAD;
        unsigned int* mp = (unsigned int*)((char*)d_ws + 3 * bfbytes);

        hipLaunchKernelGGL(prep_qk,   dim3(4096),  dim3(256), 0, stream, Q, K, scale, Qb, Kb);
        hipLaunchKernelGGL(prep_vt,   dim3(1024),  dim3(256), 0, stream, V, VbT);
        hipLaunchKernelGGL(prep_mask, dim3(32768), dim3(256), 0, stream, mask, mp);
        hipLaunchKernelGGL(sdpa_main, dim3(1024),  dim3(256), 0, stream,
                           Qb, Kb, VbT, mp, ctx_out, attn_out);
    } else {
        hipLaunchKernelGGL(sdpa_fallback, dim3(1024), dim3(256), 0, stream,
                           Q, K, V, scale, mask, ctx_out, attn_out);
    }
}

// Round 8
// 181.378 us; speedup vs baseline: 2.2864x; 1.1315x over previous
//
#include <hip/hip_runtime.h>
#include <hip/hip_bf16.h>
#include <cstdint>

// Problem constants: B=2, H=16, L=2048, D=64
#define L_SEQ 2048
#define D_HEAD 64
#define N_HEADS 16
#define NBH 32   // B*H

typedef __attribute__((ext_vector_type(8))) __bf16 bf16x8;
typedef __attribute__((ext_vector_type(4))) __bf16 bf16x4;
typedef __attribute__((ext_vector_type(4))) float f32x4;

// ============================ prep kernels ============================

// Qb = bf16(Q * scale * log2e)  (so epilogue is exp2);  Kb = bf16(K)
__global__ __launch_bounds__(256) void prep_qk(const float* __restrict__ Q,
                                               const float* __restrict__ K,
                                               const float* __restrict__ scale_p,
                                               __bf16* __restrict__ Qb,
                                               __bf16* __restrict__ Kb) {
    const float c = scale_p[0] * 1.4426950408889634f;
    const size_t i = ((size_t)blockIdx.x * 256 + threadIdx.x) * 4;
    float4 q = *(const float4*)(Q + i);
    float4 k = *(const float4*)(K + i);
    __bf16 qo[4], ko[4];
    qo[0] = (__bf16)(q.x * c); qo[1] = (__bf16)(q.y * c);
    qo[2] = (__bf16)(q.z * c); qo[3] = (__bf16)(q.w * c);
    ko[0] = (__bf16)k.x; ko[1] = (__bf16)k.y; ko[2] = (__bf16)k.z; ko[3] = (__bf16)k.w;
    *(bf16x4*)(Qb + i) = *(bf16x4*)qo;
    *(bf16x4*)(Kb + i) = *(bf16x4*)ko;
}

// VbT[bh][d][k] = bf16(V[bh][k][d])  -- tiled transpose through LDS
__global__ __launch_bounds__(256) void prep_vt(const float* __restrict__ V,
                                               __bf16* __restrict__ VbT) {
    __shared__ __bf16 tile[64][72];
    const int bh = blockIdx.x >> 5;
    const int kt = blockIdx.x & 31;
    const int tid = threadIdx.x;
    const int r = tid >> 2;          // 0..63
    const int c = (tid & 3) * 16;    // 0,16,32,48
    const float* src = V + ((size_t)bh * L_SEQ + (size_t)kt * 64 + r) * D_HEAD + c;
    #pragma unroll
    for (int i = 0; i < 4; ++i) {
        float4 f = ((const float4*)src)[i];
        tile[r][c + i * 4 + 0] = (__bf16)f.x;
        tile[r][c + i * 4 + 1] = (__bf16)f.y;
        tile[r][c + i * 4 + 2] = (__bf16)f.z;
        tile[r][c + i * 4 + 3] = (__bf16)f.w;
    }
    __syncthreads();
    __bf16 out[16];
    #pragma unroll
    for (int j = 0; j < 16; ++j) out[j] = tile[c + j][r];   // [k][d] -> row d
    __bf16* dst = VbT + ((size_t)bh * D_HEAD + r) * L_SEQ + (size_t)kt * 64 + c;
    *(bf16x8*)dst       = *(bf16x8*)&out[0];
    *(bf16x8*)(dst + 8) = *(bf16x8*)&out[8];
}

// pack mask int32 -> bit per k: mp[row][kword], row in [B*L), 64 words/row
__global__ __launch_bounds__(256) void prep_mask(const int* __restrict__ mask,
                                                 unsigned int* __restrict__ mp) {
    const int wv   = blockIdx.x * 4 + (threadIdx.x >> 6);
    const int lane = threadIdx.x & 63;
    const int row  = wv >> 5;            // 0..4095
    const int k0   = (wv & 31) * 64;
    const int m = mask[(size_t)row * L_SEQ + k0 + lane];
    const unsigned long long b = __ballot(m != 0);
    if (lane < 2) mp[row * 64 + (k0 >> 5) + lane] = (unsigned int)(b >> (32 * lane));
}

// ============================ main kernel ============================
// R7 diagnosis: CU saturated on aggregate VALU+LDS issue (not latency).
// This round: SWAPPED QK^T -> mfma(A=K, B=Q) computes S^T, so each lane owns
// 4 CONSECUTIVE k for one q-row (q = lane&15):
//  - P scatter becomes 4x ds_write_b64 (was 16x ds_write_b16)
//  - mask: 1 uint2 load per lane per chunk (own row), lane-local nibbles
//  - lsum: 1 scalar + 2 shuffles (was 4 accumulators + 16 shuffles)
// PV reads, V layout, full-line NT attn stores, ctx layout: unchanged.
__global__ __launch_bounds__(256) void sdpa_main(
    const __bf16* __restrict__ Qb, const __bf16* __restrict__ Kb,
    const __bf16* __restrict__ VbT, const unsigned int* __restrict__ mp,
    float* __restrict__ ctx_out, float* __restrict__ attn_out)
{
    __shared__ __bf16 K_lds[64][72];
    __shared__ __bf16 V_lds[64][72];   // [d][k_local]
    __shared__ __bf16 P_lds[4][16][72];

    const int tid = threadIdx.x;
    const int w   = tid >> 6;     // wave 0..3
    const int l   = tid & 63;     // lane
    const int r15 = l & 15;
    const int g   = l >> 4;

    // bijective XCD swizzle: 1024 blocks -> 128 consecutive work-ids per XCD
    const int bid = blockIdx.x;
    const int wg  = (bid & 7) * 128 + (bid >> 3);
    const int bh  = wg >> 5;
    const int qt  = wg & 31;
    const int b   = bh >> 4;
    const int q0  = qt * 64;

    const __bf16* Kp = Kb  + (size_t)bh * L_SEQ * D_HEAD;
    const __bf16* Vp = VbT + (size_t)bh * D_HEAD * L_SEQ;

    // this lane's q row (swapped layout: q = col = r15)
    const int qq = q0 + w * 16 + r15;

    // Q fragments (bf16, pre-scaled). Serve as the MFMA B operand:
    // B[k=8g+j][col=q=r15] = Q[r15][8g+j] -- exactly this load.
    bf16x8 aq[2];
    {
        const __bf16* qrow = Qb + ((size_t)bh * L_SEQ + qq) * D_HEAD;
        aq[0] = *(const bf16x8*)(qrow + 8 * g);
        aq[1] = *(const bf16x8*)(qrow + 32 + 8 * g);
    }

    // staging decomposition: 64x64 bf16 tile, thread -> 16 consecutive bf16
    const int srow = tid >> 2;         // 0..63
    const int scol = (tid & 3) * 16;   // 0,16,32,48

    const unsigned int* mrow = mp + ((size_t)b * L_SEQ + qq) * 64;

    float lsum = 0.f;

    // ================= Pass 1: row sums (K staging pipelined) =================
    {
        bf16x8 ka = *(const bf16x8*)(Kp + (size_t)srow * D_HEAD + scol);
        bf16x8 kb = *(const bf16x8*)(Kp + (size_t)srow * D_HEAD + scol + 8);
        *(bf16x8*)&K_lds[srow][scol]     = ka;
        *(bf16x8*)&K_lds[srow][scol + 8] = kb;
        __syncthreads();

        for (int ch = 0; ch < 32; ++ch) {
            const int chn = (ch < 31) ? ch + 1 : ch;
            const __bf16* knp = Kp + (size_t)(chn * 64 + srow) * D_HEAD + scol;
            ka = *(const bf16x8*)knp;
            kb = *(const bf16x8*)(knp + 8);

            const uint2 mw = *(const uint2*)(mrow + 2 * ch);

            f32x4 acc[4] = {{0,0,0,0},{0,0,0,0},{0,0,0,0},{0,0,0,0}};
            #pragma unroll
            for (int t = 0; t < 4; ++t) {
                // A = K rows 16t..16t+15 (lane row = r15), k-dim = d
                bf16x8 bk0 = *(const bf16x8*)&K_lds[t * 16 + r15][g * 8];
                bf16x8 bk1 = *(const bf16x8*)&K_lds[t * 16 + r15][32 + g * 8];
                acc[t] = __builtin_amdgcn_mfma_f32_16x16x32_bf16(bk0, aq[0], acc[t], 0, 0, 0);
                acc[t] = __builtin_amdgcn_mfma_f32_16x16x32_bf16(bk1, aq[1], acc[t], 0, 0, 0);
            }
            // acc[t][r] = S^T[k = 64ch + 16t + 4g + r][q = qq]
            #pragma unroll
            for (int t = 0; t < 4; ++t) {
                const unsigned int wsel = (t & 2) ? mw.y : mw.x;
                const unsigned int nib  = (wsel >> ((t & 1) * 16 + 4 * g)) & 0xFu;
                #pragma unroll
                for (int r = 0; r < 4; ++r) {
                    const float e = __builtin_exp2f(acc[t][r]);
                    lsum += ((nib >> r) & 1u) ? 0.f : e;
                }
            }

            __syncthreads();
            *(bf16x8*)&K_lds[srow][scol]     = ka;
            *(bf16x8*)&K_lds[srow][scol + 8] = kb;
            __syncthreads();
        }
    }

    // reduce across the 4 lanes sharing r15 (lanes l, l^16, l^32, l^48)
    lsum += __shfl_xor(lsum, 16);
    lsum += __shfl_xor(lsum, 32);
    const float inv = 1.0f / lsum;

    // ================= Pass 2: PV + full-line attn stores (pipelined) =========
    f32x4 ctx[4] = {{0,0,0,0},{0,0,0,0},{0,0,0,0},{0,0,0,0}};

    // attn store coords: lane stores cols sc..sc+3 of rows (4i + sr)
    const int sr = l >> 4;          // 0..3
    const int sc = (l & 15) * 4;    // 0..60
    float* abase = attn_out + ((size_t)bh * L_SEQ + q0 + w * 16) * L_SEQ;
    const int qrow_base = q0 + w * 16 + g * 4;   // ctx C rows (+r)

    {
        bf16x8 ka = *(const bf16x8*)(Kp + (size_t)srow * D_HEAD + scol);
        bf16x8 kb = *(const bf16x8*)(Kp + (size_t)srow * D_HEAD + scol + 8);
        bf16x8 va = *(const bf16x8*)(Vp + (size_t)srow * L_SEQ + scol);
        bf16x8 vb = *(const bf16x8*)(Vp + (size_t)srow * L_SEQ + scol + 8);
        __syncthreads();
        *(bf16x8*)&K_lds[srow][scol]     = ka;
        *(bf16x8*)&K_lds[srow][scol + 8] = kb;
        *(bf16x8*)&V_lds[srow][scol]     = va;
        *(bf16x8*)&V_lds[srow][scol + 8] = vb;
        __syncthreads();

        for (int ch = 0; ch < 32; ++ch) {
            const int k0 = ch * 64;
            const int chn = (ch < 31) ? ch + 1 : ch;
            const __bf16* knp = Kp + (size_t)(chn * 64 + srow) * D_HEAD + scol;
            const __bf16* vnp = Vp + (size_t)srow * L_SEQ + chn * 64 + scol;
            ka = *(const bf16x8*)knp;
            kb = *(const bf16x8*)(knp + 8);
            va = *(const bf16x8*)vnp;
            vb = *(const bf16x8*)(vnp + 8);

            const uint2 mw = *(const uint2*)(mrow + 2 * ch);

            f32x4 acc[4] = {{0,0,0,0},{0,0,0,0},{0,0,0,0},{0,0,0,0}};
            #pragma unroll
            for (int t = 0; t < 4; ++t) {
                bf16x8 bk0 = *(const bf16x8*)&K_lds[t * 16 + r15][g * 8];
                bf16x8 bk1 = *(const bf16x8*)&K_lds[t * 16 + r15][32 + g * 8];
                acc[t] = __builtin_amdgcn_mfma_f32_16x16x32_bf16(bk0, aq[0], acc[t], 0, 0, 0);
                acc[t] = __builtin_amdgcn_mfma_f32_16x16x32_bf16(bk1, aq[1], acc[t], 0, 0, 0);
            }
            // epilogue: p = exp2(s)*inv (masked); 4 consecutive k per write
            #pragma unroll
            for (int t = 0; t < 4; ++t) {
                const unsigned int wsel = (t & 2) ? mw.y : mw.x;
                const unsigned int nib  = (wsel >> ((t & 1) * 16 + 4 * g)) & 0xFu;
                __bf16 pb[4];
                #pragma unroll
                for (int r = 0; r < 4; ++r) {
                    float e = __builtin_exp2f(acc[t][r]) * inv;
                    e = ((nib >> r) & 1u) ? 0.f : e;
                    pb[r] = (__bf16)e;
                }
                // P_lds[q=r15][k_local = 16t+4g .. +3] -- one ds_write_b64
                *(bf16x4*)&P_lds[w][r15][16 * t + 4 * g] = *(bf16x4*)pb;
            }
            // PV: A = P (row q=r15, k contiguous), B = V^T. Wave-private LDS.
            const bf16x8 pa0 = *(const bf16x8*)&P_lds[w][r15][8 * g];
            const bf16x8 pa1 = *(const bf16x8*)&P_lds[w][r15][32 + 8 * g];
            #pragma unroll
            for (int t2 = 0; t2 < 4; ++t2) {
                bf16x8 pv0 = *(const bf16x8*)&V_lds[t2 * 16 + r15][8 * g];
                bf16x8 pv1 = *(const bf16x8*)&V_lds[t2 * 16 + r15][32 + 8 * g];
                ctx[t2] = __builtin_amdgcn_mfma_f32_16x16x32_bf16(pa0, pv0, ctx[t2], 0, 0, 0);
                ctx[t2] = __builtin_amdgcn_mfma_f32_16x16x32_bf16(pa1, pv1, ctx[t2], 0, 0, 0);
            }
            // attn store from P_lds: 4 rows x 256B contiguous per instr
            #pragma unroll
            for (int i = 0; i < 4; ++i) {
                const int row = 4 * i + sr;
                const uint2 raw = *(const uint2*)&P_lds[w][row][sc];
                f32x4 o;
                o[0] = __uint_as_float(raw.x << 16);
                o[1] = __uint_as_float(raw.x & 0xFFFF0000u);
                o[2] = __uint_as_float(raw.y << 16);
                o[3] = __uint_as_float(raw.y & 0xFFFF0000u);
                __builtin_nontemporal_store(o, (f32x4*)(abase + (size_t)row * L_SEQ + k0 + sc));
            }

            __syncthreads();
            *(bf16x8*)&K_lds[srow][scol]     = ka;
            *(bf16x8*)&K_lds[srow][scol + 8] = kb;
            *(bf16x8*)&V_lds[srow][scol]     = va;
            *(bf16x8*)&V_lds[srow][scol + 8] = vb;
            __syncthreads();
        }
    }

    // ctx store: C row = 4g + r (q), col = 16t2 + r15 (d)
    #pragma unroll
    for (int t2 = 0; t2 < 4; ++t2) {
        #pragma unroll
        for (int r = 0; r < 4; ++r) {
            __builtin_nontemporal_store(
                ctx[t2][r],
                &ctx_out[((size_t)bh * L_SEQ + qrow_base + r) * D_HEAD + t2 * 16 + r15]);
        }
    }
}

// ===================== fallback (round-1 verified kernel) =====================
__global__ __launch_bounds__(256) void sdpa_fallback(
    const float* __restrict__ Q, const float* __restrict__ K,
    const float* __restrict__ V, const float* __restrict__ scale_p,
    const int* __restrict__ mask, float* __restrict__ ctx_out,
    float* __restrict__ attn_out)
{
    __shared__ __bf16 K_lds[64][72];
    __shared__ __bf16 V_lds[64][72];
    __shared__ __bf16 P_lds[4][16][72];

    const int tid = threadIdx.x;
    const int w   = tid >> 6;
    const int l   = tid & 63;
    const int r15 = l & 15;
    const int g   = l >> 4;

    const int qt = blockIdx.x & 31;
    const int bh = blockIdx.x >> 5;
    const int b  = bh >> 4;
    const int q0 = qt * 64;

    const float scale = *scale_p;
    const float* Qp = Q + (size_t)bh * L_SEQ * D_HEAD;
    const float* Kp = K + (size_t)bh * L_SEQ * D_HEAD;
    const float* Vp = V + (size_t)bh * L_SEQ * D_HEAD;
    const int*   Mp = mask + (size_t)b * L_SEQ * L_SEQ;

    bf16x8 aq[2];
    {
        const float* qrow = Qp + (size_t)(q0 + w * 16 + r15) * D_HEAD;
        #pragma unroll
        for (int kk = 0; kk < 2; ++kk) {
            const float* s = qrow + kk * 32 + g * 8;
            bf16x8 v;
            #pragma unroll
            for (int j = 0; j < 8; ++j) v[j] = (__bf16)s[j];
            aq[kk] = v;
        }
    }

    const int srow = tid >> 2;
    const int scol = (tid & 3) * 16;
    const int qrow_base = q0 + w * 16 + g * 4;

    float lsum[4] = {0.f, 0.f, 0.f, 0.f};

    for (int ch = 0; ch < 32; ++ch) {
        const int k0 = ch * 64;
        __syncthreads();
        {
            const float4* s4 = (const float4*)(Kp + (size_t)(k0 + srow) * D_HEAD + scol);
            __bf16 tmp[16];
            #pragma unroll
            for (int i = 0; i < 4; ++i) {
                float4 f = s4[i];
                tmp[i*4+0] = (__bf16)f.x; tmp[i*4+1] = (__bf16)f.y;
                tmp[i*4+2] = (__bf16)f.z; tmp[i*4+3] = (__bf16)f.w;
            }
            *(bf16x8*)&K_lds[srow][scol]     = *(bf16x8*)&tmp[0];
            *(bf16x8*)&K_lds[srow][scol + 8] = *(bf16x8*)&tmp[8];
        }
        __syncthreads();

        f32x4 acc[4] = {{0,0,0,0},{0,0,0,0},{0,0,0,0},{0,0,0,0}};
        #pragma unroll
        for (int t = 0; t < 4; ++t) {
            #pragma unroll
            for (int kk = 0; kk < 2; ++kk) {
                bf16x8 bk = *(const bf16x8*)&K_lds[t * 16 + r15][kk * 32 + g * 8];
                acc[t] = __builtin_amdgcn_mfma_f32_16x16x32_bf16(aq[kk], bk, acc[t], 0, 0, 0);
            }
        }
        #pragma unroll
        for (int t = 0; t < 4; ++t) {
            const int kcol = k0 + t * 16 + r15;
            #pragma unroll
            for (int r = 0; r < 4; ++r) {
                const int mk = Mp[(size_t)(qrow_base + r) * L_SEQ + kcol];
                const float s = acc[t][r] * scale;
                const float e = mk ? 0.0f : __expf(s);
                lsum[r] += e;
            }
        }
    }

    #pragma unroll
    for (int r = 0; r < 4; ++r) {
        float v = lsum[r];
        v += __shfl_xor(v, 1);
        v += __shfl_xor(v, 2);
        v += __shfl_xor(v, 4);
        v += __shfl_xor(v, 8);
        lsum[r] = 1.0f / v;
    }

    f32x4 ctx[4] = {{0,0,0,0},{0,0,0,0},{0,0,0,0},{0,0,0,0}};
    for (int ch = 0; ch < 32; ++ch) {
        const int k0 = ch * 64;
        __syncthreads();
        {
            const float4* s4 = (const float4*)(Kp + (size_t)(k0 + srow) * D_HEAD + scol);
            __bf16 tmp[16];
            #pragma unroll
            for (int i = 0; i < 4; ++i) {
                float4 f = s4[i];
                tmp[i*4+0] = (__bf16)f.x; tmp[i*4+1] = (__bf16)f.y;
                tmp[i*4+2] = (__bf16)f.z; tmp[i*4+3] = (__bf16)f.w;
            }
            *(bf16x8*)&K_lds[srow][scol]     = *(bf16x8*)&tmp[0];
            *(bf16x8*)&K_lds[srow][scol + 8] = *(bf16x8*)&tmp[8];
        }
        {
            const float4* s4 = (const float4*)(Vp + (size_t)(k0 + srow) * D_HEAD + scol);
            #pragma unroll
            for (int i = 0; i < 4; ++i) {
                float4 f = s4[i];
                V_lds[scol + i*4 + 0][srow] = (__bf16)f.x;
                V_lds[scol + i*4 + 1][srow] = (__bf16)f.y;
                V_lds[scol + i*4 + 2][srow] = (__bf16)f.z;
                V_lds[scol + i*4 + 3][srow] = (__bf16)f.w;
            }
        }
        __syncthreads();

        f32x4 acc[4] = {{0,0,0,0},{0,0,0,0},{0,0,0,0},{0,0,0,0}};
        #pragma unroll
        for (int t = 0; t < 4; ++t) {
            #pragma unroll
            for (int kk = 0; kk < 2; ++kk) {
                bf16x8 bk = *(const bf16x8*)&K_lds[t * 16 + r15][kk * 32 + g * 8];
                acc[t] = __builtin_amdgcn_mfma_f32_16x16x32_bf16(aq[kk], bk, acc[t], 0, 0, 0);
            }
        }
        #pragma unroll
        for (int t = 0; t < 4; ++t) {
            const int kcol = k0 + t * 16 + r15;
            #pragma unroll
            for (int r = 0; r < 4; ++r) {
                const int mk = Mp[(size_t)(qrow_base + r) * L_SEQ + kcol];
                const float s = acc[t][r] * scale;
                const float p = mk ? 0.0f : __expf(s) * lsum[r];
                __builtin_nontemporal_store(
                    p, &attn_out[((size_t)bh * L_SEQ + qrow_base + r) * L_SEQ + kcol]);
                P_lds[w][g * 4 + r][t * 16 + r15] = (__bf16)p;
            }
        }
        #pragma unroll
        for (int t2 = 0; t2 < 4; ++t2) {
            #pragma unroll
            for (int kk = 0; kk < 2; ++kk) {
                bf16x8 pa = *(const bf16x8*)&P_lds[w][r15][kk * 32 + g * 8];
                bf16x8 pv = *(const bf16x8*)&V_lds[t2 * 16 + r15][kk * 32 + g * 8];
                ctx[t2] = __builtin_amdgcn_mfma_f32_16x16x32_bf16(pa, pv, ctx[t2], 0, 0, 0);
            }
        }
    }

    #pragma unroll
    for (int t2 = 0; t2 < 4; ++t2) {
        #pragma unroll
        for (int r = 0; r < 4; ++r) {
            __builtin_nontemporal_store(
                ctx[t2][r],
                &ctx_out[((size_t)bh * L_SEQ + qrow_base + r) * D_HEAD + t2 * 16 + r15]);
        }
    }
}

// ============================ launcher ============================
extern "C" void kernel_launch(void* const* d_in, const int* in_sizes, int n_in,
                              void* d_out, int out_size, void* d_ws, size_t ws_size,
                              hipStream_t stream) {
    const float* Q     = (const float*)d_in[0];
    const float* K     = (const float*)d_in[1];
    const float* V     = (const float*)d_in[2];
    const float* scale = (const float*)d_in[3];
    const int*   mask  = (const int*)d_in[4];

    float* ctx_out  = (float*)d_out;
    float* attn_out = (float*)d_out + (size_t)NBH * L_SEQ * D_HEAD;

    const size_t bfbytes = (size_t)NBH * L_SEQ * D_HEAD * 2;  // 8,388,608
    const size_t need = 3 * bfbytes + (size_t)2 * L_SEQ * (L_SEQ / 32) * 4; // +1MB mask bits

    if (ws_size >= need) {
        __bf16* Qb  = (__bf16*)d_ws;
        __bf16* Kb  = Qb + (size_t)NBH * L_SEQ * D_HEAD;
        __bf16* VbT = Kb + (size_t)NBH * L_SEQ * D_HEAD;
        unsigned int* mp = (unsigned int*)((char*)d_ws + 3 * bfbytes);

        hipLaunchKernelGGL(prep_qk,   dim3(4096),  dim3(256), 0, stream, Q, K, scale, Qb, Kb);
        hipLaunchKernelGGL(prep_vt,   dim3(1024),  dim3(256), 0, stream, V, VbT);
        hipLaunchKernelGGL(prep_mask, dim3(32768), dim3(256), 0, stream, mask, mp);
        hipLaunchKernelGGL(sdpa_main, dim3(1024),  dim3(256), 0, stream,
                           Qb, Kb, VbT, mp, ctx_out, attn_out);
    } else {
        hipLaunchKernelGGL(sdpa_fallback, dim3(1024), dim3(256), 0, stream,
                           Q, K, V, scale, mask, ctx_out, attn_out);
    }
}